// Round 2
// 733.625 us; speedup vs baseline: 1.5862x; 1.5862x over previous
//
#include <hip/hip_runtime.h>
#include <hip/hip_bf16.h>

// WindowAttention fused kernel for MI355X (gfx950) — v2b (v2 resubmit).
// 4096 windows, N=64 tokens, DIM=256, NH=1. fp32 I/O, bf16 MFMA compute.
// One block per window, 1024 threads (16 waves -> 4 waves/SIMD forced,
// <=128 regs/thread). Single-shot x staging, LDS overlays (104 KB),
// coalesced float4 output via LDS bounce, XCD-contiguous block swizzle.

typedef __attribute__((ext_vector_type(8))) short short8;
typedef __attribute__((ext_vector_type(4))) float f32x4;

// fp32 -> bf16 bits, sanitizing NaN/Inf (IEEE maxNum: fmaxf(NaN,a)=a) so a
// dtype misread produces large-finite output (diagnostic), never NaN.
__device__ __forceinline__ unsigned short f2bf(float f) {
    f = fmaxf(f, -3.0e38f);
    f = fminf(f, 3.0e38f);
    __hip_bfloat16 h = __float2bfloat16(f);
    return *reinterpret_cast<unsigned short*>(&h);
}
__device__ __forceinline__ float sane(float f) {
    f = fmaxf(f, -1.0e10f);
    return fminf(f, 1.0e10f);
}

// ---------------------------------------------------------------- prep ----
// One kernel: repack qkv_w (256x768) + proj_w (256x256) into bf16 MFMA
// B-fragment order, and build btab[t][i][j] = A_phi + A_th (64 x 64 x 64).
// B-frag order: idx = ((ntile*8 + ktile)*64 + lane)*8 + j
//   <->  W[k = 32*ktile + 8*(lane>>4) + j][n = 16*ntile + (lane&15)]
__global__ void prep_all(const float* __restrict__ qkv_w,
                         const float* __restrict__ proj_w,
                         const float* __restrict__ theta_max,
                         const float* __restrict__ a_p,
                         const float* __restrict__ b_p,
                         const float* __restrict__ a_r,
                         const float* __restrict__ b_r,
                         unsigned short* __restrict__ wq_pack,
                         unsigned short* __restrict__ wp_pack,
                         float* __restrict__ btab) {
    int t = blockIdx.x * blockDim.x + threadIdx.x;
    if (t < 24576) {             // 48 ntiles * 8 ktiles * 64 lanes
        int lane = t & 63, kt = (t >> 6) & 7, nt = t >> 9;
        int k0 = kt * 32 + (lane >> 4) * 8;
        int n  = nt * 16 + (lane & 15);
        unsigned short* dst = wq_pack + t * 8;
        for (int j = 0; j < 8; ++j) dst[j] = f2bf(qkv_w[(k0 + j) * 768 + n]);
    } else if (t < 32768) {      // 16 ntiles * 8 ktiles * 64 lanes
        int t2 = t - 24576;
        int lane = t2 & 63, kt = (t2 >> 6) & 7, nt = t2 >> 9;
        int k0 = kt * 32 + (lane >> 4) * 8;
        int n  = nt * 16 + (lane & 15);
        unsigned short* dst = wp_pack + t2 * 8;
        for (int j = 0; j < 8; ++j) dst[j] = f2bf(proj_w[(k0 + j) * 256 + n]);
    } else {
        int idx = t - 32768;
        if (idx >= 64 * 4096) return;
        int tt = idx >> 12, ij = idx & 4095, i = ij >> 6, j = ij & 63;
        int ri = (i >> 3) - (j >> 3);          // radius (y diff) in [-7,7]
        int az = (i & 7) - (j & 7);            // azimuth (x diff) in [-7,7]
        int azi = az < 0 ? az + 15 : az;       // torch negative wrap: mod 15
        int rii = ri < 0 ? ri + 15 : ri;
        float ang = (float)az * (6.28318530717958647692f / 64.0f);
        float aphi = a_p[azi] * cosf(ang) + b_p[azi] * sinf(ang);
        float rn = (float)ri * theta_max[tt] * (1.0f / 64.0f);
        float ath = a_r[rii] * cosf(rn) + b_r[rii] * sinf(rn);
        btab[idx] = sane(aphi + ath);
    }
}

// ---------------------------------------------------------------- main ----
// LDS layout (byte offsets), 1024 threads:
//   kbuf   0      .. 33792   64x264 ushort (K)      -> later Pbuf (64x72), rbuf
//   qbuf   33792  .. 67584   64x264 ushort (Q*scale)-> later ao, rbuf tail
//   vt     67584  .. 104448  256x72 ushort (V^T)    <- earlier xbuf (64x264)
//   pmaxs  104448 .. 105472  256 f32  [row*4 + ntq]
//   psums  105472 .. 106496  256 f32
//   rbuf = smem base, 64x260 f32 (66560 B, fits in kbuf+qbuf = 67584 B)
#define LDS_BYTES 106496

__global__ __launch_bounds__(1024, 1)
void wattn_main(const float* __restrict__ x,
                const float* __restrict__ qkv_b,
                const float* __restrict__ proj_b,
                const unsigned short* __restrict__ wq_pack,
                const unsigned short* __restrict__ wp_pack,
                const float* __restrict__ btab,
                float* __restrict__ out) {
    extern __shared__ char smem[];
    unsigned short* kbuf = (unsigned short*)smem;
    unsigned short* qbuf = kbuf + 16896;
    unsigned short* vt   = qbuf + 16896;
    unsigned short* xbuf = vt;                    // overlay: xbuf dead before vt written
    float* pmaxs = (float*)(smem + 104448);
    float* psums = pmaxs + 256;
    float* rbuf  = (float*)smem;                  // overlay: written after all P/ao reads

    const int tid = threadIdx.x;
    const int w = tid >> 6, lane = tid & 63;
    const int g = lane >> 4, c = lane & 15;
    // XCD-contiguous bijective swizzle: 4096 blocks, 8 XCDs, 512 per XCD.
    // Windows sharing a btab slice (b>>6) land on one XCD's L2.
    const int bid = blockIdx.x;
    const int b = (bid & 7) * 512 + (bid >> 3);
    const float* xb = x + (size_t)b * 16384;

    // ======== stage x (64x256 fp32 -> bf16, stride 264). Loads first (ILP).
    float4 xv[4];
#pragma unroll
    for (int i = 0; i < 4; ++i) {
        int ch = tid + i * 1024;                  // 4096 float4 chunks
        xv[i] = *(const float4*)(xb + (ch >> 6) * 256 + (ch & 63) * 4);
    }
#pragma unroll
    for (int i = 0; i < 4; ++i) {
        int ch = tid + i * 1024;
        unsigned short* dst = xbuf + (ch >> 6) * 264 + (ch & 63) * 4;
        dst[0] = f2bf(xv[i].x); dst[1] = f2bf(xv[i].y);
        dst[2] = f2bf(xv[i].z); dst[3] = f2bf(xv[i].w);
    }
    __syncthreads();

    // ======== GEMM1: qkv = x @ Wqkv (+b). wave w owns out cols 48w..48w+47.
    f32x4 acc[3][4];
#pragma unroll
    for (int nt = 0; nt < 3; ++nt)
#pragma unroll
        for (int mt = 0; mt < 4; ++mt)
            acc[nt][mt] = f32x4{0.f, 0.f, 0.f, 0.f};

#pragma unroll
    for (int q4 = 0; q4 < 4; ++q4) {              // K quarter: ktiles q4*2, q4*2+1
        short8 af[4][2];
#pragma unroll
        for (int mt = 0; mt < 4; ++mt)
#pragma unroll
            for (int k2 = 0; k2 < 2; ++k2)
                af[mt][k2] = *(const short8*)(xbuf + (mt * 16 + c) * 264 + (q4 * 2 + k2) * 32 + g * 8);
#pragma unroll
        for (int nt = 0; nt < 3; ++nt) {
            int ntg = w * 3 + nt;
            short8 bfr[2];
#pragma unroll
            for (int k2 = 0; k2 < 2; ++k2)
                bfr[k2] = *(const short8*)(wq_pack + ((size_t)(ntg * 8 + q4 * 2 + k2) * 64 + lane) * 8);
#pragma unroll
            for (int mt = 0; mt < 4; ++mt)
#pragma unroll
                for (int k2 = 0; k2 < 2; ++k2)
                    acc[nt][mt] = __builtin_amdgcn_mfma_f32_16x16x32_bf16(
                        af[mt][k2], bfr[k2], acc[nt][mt], 0, 0, 0);
        }
    }
    __syncthreads();   // all xbuf reads done before vt (same region) is written

    // epilogue: +bias, scatter to q (scaled), k, v^T
#pragma unroll
    for (int nt = 0; nt < 3; ++nt) {
        int ntg = w * 3 + nt;
        int col = ntg * 16 + c;
        float bias = sane(qkv_b[col]);
#pragma unroll
        for (int mt = 0; mt < 4; ++mt)
#pragma unroll
            for (int rr = 0; rr < 4; ++rr) {
                int row = mt * 16 + g * 4 + rr;
                float v = acc[nt][mt][rr] + bias;
                if (ntg < 16)       qbuf[row * 264 + col] = f2bf(v * 0.0625f);  // SCALE=1/16
                else if (ntg < 32)  kbuf[row * 264 + (col - 256)] = f2bf(v);
                else                vt[(col - 512) * 72 + row] = f2bf(v);
            }
    }
    __syncthreads();

    // ======== QK^T + bias + softmax. wave w: row tile w>>2, col tile w&3.
    const int mtq = w >> 2, ntq = w & 3;
    const float* bt = btab + (size_t)(b >> 6) * 4096;
    float bias_r[4];
#pragma unroll
    for (int rr = 0; rr < 4; ++rr)
        bias_r[rr] = bt[(mtq * 16 + g * 4 + rr) * 64 + ntq * 16 + c];
    f32x4 sacc = f32x4{0.f, 0.f, 0.f, 0.f};
#pragma unroll
    for (int kt = 0; kt < 8; ++kt) {
        short8 aq = *(const short8*)(qbuf + (mtq * 16 + c) * 264 + kt * 32 + g * 8);
        short8 bk = *(const short8*)(kbuf + (ntq * 16 + c) * 264 + kt * 32 + g * 8);
        sacc = __builtin_amdgcn_mfma_f32_16x16x32_bf16(aq, bk, sacc, 0, 0, 0);
    }
    float mloc[4];
#pragma unroll
    for (int rr = 0; rr < 4; ++rr) {
        float s = sacc[rr] + bias_r[rr];
        sacc[rr] = s;
        float mx = s;
        mx = fmaxf(mx, __shfl_xor(mx, 1, 16));
        mx = fmaxf(mx, __shfl_xor(mx, 2, 16));
        mx = fmaxf(mx, __shfl_xor(mx, 4, 16));
        mx = fmaxf(mx, __shfl_xor(mx, 8, 16));
        mloc[rr] = mx;
    }
    if (c == 0)
#pragma unroll
        for (int rr = 0; rr < 4; ++rr)
            pmaxs[(mtq * 16 + g * 4 + rr) * 4 + ntq] = mloc[rr];
    __syncthreads();

    unsigned short* Pbuf = kbuf;   // 64 x 72 bf16, overlays dead k
#pragma unroll
    for (int rr = 0; rr < 4; ++rr) {
        int row = mtq * 16 + g * 4 + rr;
        float m = fmaxf(fmaxf(pmaxs[row * 4 + 0], pmaxs[row * 4 + 1]),
                        fmaxf(pmaxs[row * 4 + 2], pmaxs[row * 4 + 3]));
        float p = __expf(sacc[rr] - m);
        float s = p;
        s += __shfl_xor(s, 1, 16);
        s += __shfl_xor(s, 2, 16);
        s += __shfl_xor(s, 4, 16);
        s += __shfl_xor(s, 8, 16);
        if (c == 0) psums[row * 4 + ntq] = s;
        Pbuf[row * 72 + ntq * 16 + c] = f2bf(p);
    }
    __syncthreads();

    // ======== PV: wave w owns out dims 16w..16w+15. K = 64 tokens.
    f32x4 oacc[4];
#pragma unroll
    for (int mt = 0; mt < 4; ++mt) oacc[mt] = f32x4{0.f, 0.f, 0.f, 0.f};
#pragma unroll
    for (int kt = 0; kt < 2; ++kt) {
        short8 bv = *(const short8*)(vt + (w * 16 + c) * 72 + kt * 32 + g * 8);
#pragma unroll
        for (int mt = 0; mt < 4; ++mt) {
            short8 ap = *(const short8*)(Pbuf + (mt * 16 + c) * 72 + kt * 32 + g * 8);
            oacc[mt] = __builtin_amdgcn_mfma_f32_16x16x32_bf16(ap, bv, oacc[mt], 0, 0, 0);
        }
    }
    // normalize by softmax denom, write ao (overlays qbuf — q is dead)
    unsigned short* aobuf = qbuf;
#pragma unroll
    for (int mt = 0; mt < 4; ++mt)
#pragma unroll
        for (int rr = 0; rr < 4; ++rr) {
            int lr = g * 4 + rr, row = mt * 16 + lr;
            float l = psums[row * 4 + 0] + psums[row * 4 + 1]
                    + psums[row * 4 + 2] + psums[row * 4 + 3];
            float inv = 1.0f / l;
            aobuf[row * 264 + w * 16 + c] = f2bf(oacc[mt][rr] * inv);
        }
    __syncthreads();

    // ======== proj: out = ao @ Wproj + b. wave w owns out cols 16w..16w+15.
    f32x4 pacc[4];
#pragma unroll
    for (int mt = 0; mt < 4; ++mt) pacc[mt] = f32x4{0.f, 0.f, 0.f, 0.f};
#pragma unroll
    for (int kt = 0; kt < 8; ++kt) {
        short8 bp = *(const short8*)(wp_pack + ((size_t)(w * 8 + kt) * 64 + lane) * 8);
#pragma unroll
        for (int mt = 0; mt < 4; ++mt) {
            short8 aa = *(const short8*)(aobuf + (mt * 16 + c) * 264 + kt * 32 + g * 8);
            pacc[mt] = __builtin_amdgcn_mfma_f32_16x16x32_bf16(aa, bp, pacc[mt], 0, 0, 0);
        }
    }
    __syncthreads();   // all Pbuf/aobuf reads done before rbuf (same region) writes

    // stage result fp32 into rbuf (stride 260 breaks bank alignment), then
    // sweep out as contiguous float4 rows (1 KB per wave instruction).
    float pb = sane(proj_b[w * 16 + c]);
#pragma unroll
    for (int mt = 0; mt < 4; ++mt)
#pragma unroll
        for (int rr = 0; rr < 4; ++rr)
            rbuf[(mt * 16 + g * 4 + rr) * 260 + w * 16 + c] = pacc[mt][rr] + pb;
    __syncthreads();

    float* ob = out + (size_t)b * 16384;
#pragma unroll
    for (int i = 0; i < 4; ++i) {
        int ch = tid + i * 1024;
        float4 vv = *(const float4*)(rbuf + (ch >> 6) * 260 + (ch & 63) * 4);
        *(float4*)(ob + (ch >> 6) * 256 + (ch & 63) * 4) = vv;
    }
}

// -------------------------------------------------------------- launch ----
extern "C" void kernel_launch(void* const* d_in, const int* in_sizes, int n_in,
                              void* d_out, int out_size, void* d_ws, size_t ws_size,
                              hipStream_t stream) {
    const float* x      = (const float*)d_in[0];
    const float* theta  = (const float*)d_in[1];
    const float* qkv_w  = (const float*)d_in[2];
    const float* qkv_b  = (const float*)d_in[3];
    const float* proj_w = (const float*)d_in[4];
    const float* proj_b = (const float*)d_in[5];
    const float* a_p    = (const float*)d_in[6];
    const float* b_p    = (const float*)d_in[7];
    const float* a_r    = (const float*)d_in[8];
    const float* b_r    = (const float*)d_in[9];
    float* out = (float*)d_out;

    // workspace: wq_pack (393216 B) | wp_pack (131072 B) | btab (1 MB)
    unsigned short* wq_pack = (unsigned short*)d_ws;
    unsigned short* wp_pack = wq_pack + 196608;
    float* btab = (float*)((char*)d_ws + 524288);

    // 32768 repack threads + 262144 bias threads = 294912 -> 1152 blocks
    prep_all<<<1152, 256, 0, stream>>>(qkv_w, proj_w, theta, a_p, b_p, a_r, b_r,
                                       wq_pack, wp_pack, btab);

    hipFuncSetAttribute(reinterpret_cast<const void*>(wattn_main),
                        hipFuncAttributeMaxDynamicSharedMemorySize, LDS_BYTES);
    wattn_main<<<4096, 1024, LDS_BYTES, stream>>>(x, qkv_b, proj_b, wq_pack, wp_pack, btab, out);
}

// Round 4
// 723.010 us; speedup vs baseline: 1.6095x; 1.0147x over previous
//
#include <hip/hip_runtime.h>
#include <hip/hip_bf16.h>

// WindowAttention fused kernel for MI355X (gfx950) — v3 (resubmit, infra flake).
// 4096 windows, N=64 tokens, DIM=256, NH=1. fp32 I/O, bf16 MFMA compute.
// Key change vs v2: Q,K never materialized. Prep computes M = Wq*Wk^T so
// S = scale*(x M x^T + u_i + w_j + c0). Peak LDS drops to 76 KB -> 2 blocks
// co-resident per CU (512 threads, 8 waves each) to overlap phase barriers.
// All LDS tiles power-of-2 stride with XOR-16B-block swizzle.

typedef __attribute__((ext_vector_type(8))) short short8;
typedef __attribute__((ext_vector_type(4))) short short4v;
typedef __attribute__((ext_vector_type(4))) float f32x4;

#define SCALE_ATT 0.0625f   // (DIM/NH)^-0.5 = 1/16

// fp32 -> bf16 bits, sanitizing NaN/Inf so a dtype misread produces
// large-finite output (diagnostic), never NaN.
__device__ __forceinline__ unsigned short f2bf(float f) {
    f = fmaxf(f, -3.0e38f);
    f = fminf(f, 3.0e38f);
    __hip_bfloat16 h = __float2bfloat16(f);
    return *reinterpret_cast<unsigned short*>(&h);
}
__device__ __forceinline__ float bf2f(unsigned short u) {
    unsigned int b = ((unsigned int)u) << 16;
    float f;
    __builtin_memcpy(&f, &b, 4);
    return f;
}
__device__ __forceinline__ float sane(float f) {
    f = fmaxf(f, -1.0e10f);
    return fminf(f, 1.0e10f);
}

// Swizzled index helpers (ushort-element index). 16B block = 8 ushorts;
// XOR the low 3 block bits by (row&7) so 16 rows at one column spread banks.
#define SWX(r, c) ((r) * 256 + ((c) ^ (((r) & 7) << 3)))   // 64x256 ushort
#define SWV(d, t) ((d) * 64 + ((t) ^ (((d) & 7) << 3)))    // 256x64 ushort
#define SWR(r, c) ((r) * 256 + ((c) ^ (((r) & 7) << 2)))   // 64x256 float

// ---------------------------------------------------------------- prep ----
// One kernel, branch by blockIdx.x:
//  [0,256)   : M = Wq @ Wk^T tiles (16x16 per block, K=256, LDS-staged fp32),
//              packed *scale into bf16 B-frag order.
//  256       : qb2[d] = scale * sum_dq Wq[d][dq]*bk[dq]; qb2[256] = scale*bq.bk
//  257       : kb2[d] = scale * sum_dq Wk[d][dq]*bq[dq]
//  [258,290) : wv_pack  (Wv = qkv_w cols 512:768, B-frag order)
//  [290,322) : wp_pack  (proj_w, B-frag order)
//  [322,1346): btab[t][i][j] = A_phi + A_th  (64 x 64 x 64 fp32)
// B-frag order: idx = ((ntile*8 + ktile)*64 + lane)*8 + j
//   <->  W[k = 32*ktile + 8*(lane>>4) + j][n = 16*ntile + (lane&15)]
__global__ void prep_all(const float* __restrict__ qkv_w,
                         const float* __restrict__ proj_w,
                         const float* __restrict__ qkv_b,
                         const float* __restrict__ theta_max,
                         const float* __restrict__ a_p,
                         const float* __restrict__ b_p,
                         const float* __restrict__ a_r,
                         const float* __restrict__ b_r,
                         unsigned short* __restrict__ m_pack,
                         unsigned short* __restrict__ wv_pack,
                         unsigned short* __restrict__ wp_pack,
                         float* __restrict__ qb2,
                         float* __restrict__ kb2,
                         float* __restrict__ btab) {
    __shared__ float sA[16][257];
    __shared__ float sB[16][257];
    const int blk = blockIdx.x, tid = threadIdx.x;
    if (blk < 256) {
        // M tile (rows 16*bi.., cols 16*bj..): M[a][b] = sum_dq Wq[a][dq]*Wk[b][dq]
        int bi = blk >> 4, bj = blk & 15;
        int row = tid >> 4, seg = tid & 15;
        const float* pa = qkv_w + (size_t)(bi * 16 + row) * 768 + seg * 16;
        const float* pb = qkv_w + (size_t)(bj * 16 + row) * 768 + 256 + seg * 16;
        for (int q = 0; q < 4; ++q) {
            float4 va = *(const float4*)(pa + q * 4);
            float4 vb = *(const float4*)(pb + q * 4);
            int cc = seg * 16 + q * 4;
            sA[row][cc + 0] = va.x; sA[row][cc + 1] = va.y;
            sA[row][cc + 2] = va.z; sA[row][cc + 3] = va.w;
            sB[row][cc + 0] = vb.x; sB[row][cc + 1] = vb.y;
            sB[row][cc + 2] = vb.z; sB[row][cc + 3] = vb.w;
        }
        __syncthreads();
        int i = tid >> 4, n = tid & 15;
        float d = 0.f;
        for (int dq = 0; dq < 256; ++dq) d = fmaf(sA[i][dq], sB[n][dq], d);
        int a = bi * 16 + i;                       // K index of T-GEMM
        int nt = bj, kt = a >> 5, lane = ((a >> 3) & 3) * 16 + n, j = a & 7;
        m_pack[(size_t)((nt * 8 + kt) * 64 + lane) * 8 + j] = f2bf(d * SCALE_ATT);
    } else if (blk == 256) {
        float s = 0.f;
        for (int dq = 0; dq < 256; ++dq)
            s = fmaf(qkv_w[(size_t)tid * 768 + dq], qkv_b[256 + dq], s);
        qb2[tid] = s * SCALE_ATT;
        if (tid == 0) {
            float cc = 0.f;
            for (int dq = 0; dq < 256; ++dq)
                cc = fmaf(qkv_b[dq], qkv_b[256 + dq], cc);
            qb2[256] = cc * SCALE_ATT;
        }
    } else if (blk == 257) {
        float s = 0.f;
        for (int dq = 0; dq < 256; ++dq)
            s = fmaf(qkv_w[(size_t)tid * 768 + 256 + dq], qkv_b[dq], s);
        kb2[tid] = s * SCALE_ATT;
    } else if (blk < 290) {
        int t2 = (blk - 258) * 256 + tid;          // [0, 8192)
        int lane = t2 & 63, kt = (t2 >> 6) & 7, nt = t2 >> 9;
        int k0 = kt * 32 + (lane >> 4) * 8, n = nt * 16 + (lane & 15);
        unsigned short* dst = wv_pack + (size_t)t2 * 8;
        for (int j = 0; j < 8; ++j) dst[j] = f2bf(qkv_w[(size_t)(k0 + j) * 768 + 512 + n]);
    } else if (blk < 322) {
        int t2 = (blk - 290) * 256 + tid;          // [0, 8192)
        int lane = t2 & 63, kt = (t2 >> 6) & 7, nt = t2 >> 9;
        int k0 = kt * 32 + (lane >> 4) * 8, n = nt * 16 + (lane & 15);
        unsigned short* dst = wp_pack + (size_t)t2 * 8;
        for (int j = 0; j < 8; ++j) dst[j] = f2bf(proj_w[(size_t)(k0 + j) * 256 + n]);
    } else {
        int idx = (blk - 322) * 256 + tid;         // [0, 262144)
        int tt = idx >> 12, ij = idx & 4095, i = ij >> 6, j = ij & 63;
        int ri = (i >> 3) - (j >> 3);              // radius (y diff) in [-7,7]
        int az = (i & 7) - (j & 7);                // azimuth (x diff) in [-7,7]
        int azi = az < 0 ? az + 15 : az;           // torch negative wrap: mod 15
        int rii = ri < 0 ? ri + 15 : ri;
        float ang = (float)az * (6.28318530717958647692f / 64.0f);
        float aphi = a_p[azi] * cosf(ang) + b_p[azi] * sinf(ang);
        float rn = (float)ri * theta_max[tt] * (1.0f / 64.0f);
        float ath = a_r[rii] * cosf(rn) + b_r[rii] * sinf(rn);
        btab[idx] = sane(aphi + ath);
    }
}

// ---------------------------------------------------------------- main ----
// LDS layout (byte offsets), 512 threads / 8 waves, 76288 B -> 2 blocks/CU:
//   xb16 [0,32768)      64x256 ushort swz: x  -> (dead after V-MFMA) -> ao
//   tb16 [32768,65536)  64x256 ushort swz: T  -> (dead after S) -> vt 256x64
//   Pb   [65536,74752)  64x72 ushort (softmax P)
//   u/w/pmaxs/psums [74752,76288)
//   rbuf = fp32 64x256 swz overlaying [0,65536) for the output bounce.
#define LDS_BYTES 76288

__global__ __launch_bounds__(512, 4)
void wattn_main(const float* __restrict__ x,
                const float* __restrict__ qkv_b,
                const float* __restrict__ proj_b,
                const unsigned short* __restrict__ m_pack,
                const unsigned short* __restrict__ wv_pack,
                const unsigned short* __restrict__ wp_pack,
                const float* __restrict__ qb2,
                const float* __restrict__ kb2,
                const float* __restrict__ btab,
                float* __restrict__ out) {
    extern __shared__ char smem[];
    unsigned short* xb16 = (unsigned short*)smem;
    unsigned short* tb16 = xb16 + 16384;
    unsigned short* Pb   = xb16 + 32768;
    float* uarr  = (float*)(smem + 74752);   // 64
    float* warr  = uarr + 64;                // 64
    float* pmaxs = uarr + 128;               // 128: [row*2 + colhalf]
    float* psums = uarr + 256;               // 128
    float* rbuf  = (float*)smem;

    const int tid = threadIdx.x;
    const int w = tid >> 6, lane = tid & 63;
    const int g = lane >> 4, c = lane & 15;
    // XCD-contiguous bijective swizzle: 4096 blocks, 8 XCDs, 512 per XCD.
    const int bid = blockIdx.x;
    const int b = (bid & 7) * 512 + (bid >> 3);
    const float* xb = x + (size_t)b * 16384;

    // ======== P0: stage x (64x256 fp32 -> bf16, swizzled). Loads first.
    float4 xv[8];
#pragma unroll
    for (int i = 0; i < 8; ++i) {
        int ch = tid + i * 512;                   // 4096 float4 chunks
        xv[i] = *(const float4*)(xb + (ch >> 6) * 256 + (ch & 63) * 4);
    }
#pragma unroll
    for (int i = 0; i < 8; ++i) {
        int ch = tid + i * 512;
        short4v s4;
        s4[0] = (short)f2bf(xv[i].x); s4[1] = (short)f2bf(xv[i].y);
        s4[2] = (short)f2bf(xv[i].z); s4[3] = (short)f2bf(xv[i].w);
        *(short4v*)(xb16 + SWX(ch >> 6, (ch & 63) * 4)) = s4;
    }
    __syncthreads();   // B0

    // ======== P0b: u_i = x_i.qb2 (+c0), w_i = x_i.kb2  (8 lanes per token)
    {
        int tok = tid >> 3, dc = tid & 7;
        float su = 0.f, sw = 0.f;
#pragma unroll
        for (int j8 = 0; j8 < 4; ++j8) {
            int d0 = dc * 32 + j8 * 8;
            short8 xs = *(const short8*)(xb16 + SWX(tok, d0));
#pragma unroll
            for (int m = 0; m < 8; ++m) {
                float xf = bf2f((unsigned short)xs[m]);
                su = fmaf(xf, qb2[d0 + m], su);
                sw = fmaf(xf, kb2[d0 + m], sw);
            }
        }
        su += __shfl_xor(su, 1, 8); su += __shfl_xor(su, 2, 8); su += __shfl_xor(su, 4, 8);
        sw += __shfl_xor(sw, 1, 8); sw += __shfl_xor(sw, 2, 8); sw += __shfl_xor(sw, 4, 8);
        if (dc == 0) {
            uarr[tok] = su + qb2[256];            // fold const bq.bk into u
            warr[tok] = sw;
        }
    }

    // ======== P1: T = x @ M  (64x256, K=256). wave w owns cols 32w..32w+31.
    {
        f32x4 tacc[2][4];
#pragma unroll
        for (int nt = 0; nt < 2; ++nt)
#pragma unroll
            for (int mt = 0; mt < 4; ++mt) tacc[nt][mt] = f32x4{0.f, 0.f, 0.f, 0.f};
#pragma unroll
        for (int q4 = 0; q4 < 4; ++q4) {
            short8 af[4][2];
#pragma unroll
            for (int mt = 0; mt < 4; ++mt)
#pragma unroll
                for (int k2 = 0; k2 < 2; ++k2)
                    af[mt][k2] = *(const short8*)(xb16 + SWX(mt * 16 + c, (q4 * 2 + k2) * 32 + g * 8));
#pragma unroll
            for (int nt = 0; nt < 2; ++nt) {
                int ntg = w * 2 + nt;
                short8 bfr[2];
#pragma unroll
                for (int k2 = 0; k2 < 2; ++k2)
                    bfr[k2] = *(const short8*)(m_pack + ((size_t)(ntg * 8 + q4 * 2 + k2) * 64 + lane) * 8);
#pragma unroll
                for (int mt = 0; mt < 4; ++mt)
#pragma unroll
                    for (int k2 = 0; k2 < 2; ++k2)
                        tacc[nt][mt] = __builtin_amdgcn_mfma_f32_16x16x32_bf16(
                            af[mt][k2], bfr[k2], tacc[nt][mt], 0, 0, 0);
            }
        }
#pragma unroll
        for (int nt = 0; nt < 2; ++nt) {
            int col = (w * 2 + nt) * 16 + c;
#pragma unroll
            for (int mt = 0; mt < 4; ++mt)
#pragma unroll
                for (int rr = 0; rr < 4; ++rr)
                    tb16[SWX(mt * 16 + g * 4 + rr, col)] = f2bf(tacc[nt][mt][rr]);
        }
    }
    __syncthreads();   // B_T

    // ======== P2: S = T @ x^T + bias -> softmax.  wave: rows 16*(w>>1), cols 32*(w&1).
    // V = x @ Wv MFMAs issued in between (independent; epilogue after B1).
    const int mtq = w >> 1, nq = w & 1;
    f32x4 sacc[2];
    sacc[0] = f32x4{0.f, 0.f, 0.f, 0.f};
    sacc[1] = f32x4{0.f, 0.f, 0.f, 0.f};
#pragma unroll
    for (int kt = 0; kt < 8; ++kt) {
        short8 aq = *(const short8*)(tb16 + SWX(mtq * 16 + c, kt * 32 + g * 8));
#pragma unroll
        for (int n2 = 0; n2 < 2; ++n2) {
            short8 bx = *(const short8*)(xb16 + SWX(nq * 32 + n2 * 16 + c, kt * 32 + g * 8));
            sacc[n2] = __builtin_amdgcn_mfma_f32_16x16x32_bf16(aq, bx, sacc[n2], 0, 0, 0);
        }
    }
    f32x4 vacc[2][4];
#pragma unroll
    for (int nt = 0; nt < 2; ++nt)
#pragma unroll
        for (int mt = 0; mt < 4; ++mt) vacc[nt][mt] = f32x4{0.f, 0.f, 0.f, 0.f};
#pragma unroll
    for (int q4 = 0; q4 < 4; ++q4) {
        short8 af[4][2];
#pragma unroll
        for (int mt = 0; mt < 4; ++mt)
#pragma unroll
            for (int k2 = 0; k2 < 2; ++k2)
                af[mt][k2] = *(const short8*)(xb16 + SWX(mt * 16 + c, (q4 * 2 + k2) * 32 + g * 8));
#pragma unroll
        for (int nt = 0; nt < 2; ++nt) {
            int ntg = w * 2 + nt;
            short8 bfr[2];
#pragma unroll
            for (int k2 = 0; k2 < 2; ++k2)
                bfr[k2] = *(const short8*)(wv_pack + ((size_t)(ntg * 8 + q4 * 2 + k2) * 64 + lane) * 8);
#pragma unroll
            for (int mt = 0; mt < 4; ++mt)
#pragma unroll
                for (int k2 = 0; k2 < 2; ++k2)
                    vacc[nt][mt] = __builtin_amdgcn_mfma_f32_16x16x32_bf16(
                        af[mt][k2], bfr[k2], vacc[nt][mt], 0, 0, 0);
        }
    }
    // bias + row-max partials
    const float* bt = btab + (size_t)(b >> 6) * 4096;
    {
        float mloc[4];
#pragma unroll
        for (int rr = 0; rr < 4; ++rr) {
            int row = mtq * 16 + g * 4 + rr;
            float uu = uarr[row];
            float s0 = sacc[0][rr] + bt[row * 64 + nq * 32 + c] + uu + warr[nq * 32 + c];
            float s1 = sacc[1][rr] + bt[row * 64 + nq * 32 + 16 + c] + uu + warr[nq * 32 + 16 + c];
            sacc[0][rr] = s0; sacc[1][rr] = s1;
            float mx = fmaxf(s0, s1);
            mx = fmaxf(mx, __shfl_xor(mx, 1, 16));
            mx = fmaxf(mx, __shfl_xor(mx, 2, 16));
            mx = fmaxf(mx, __shfl_xor(mx, 4, 16));
            mx = fmaxf(mx, __shfl_xor(mx, 8, 16));
            mloc[rr] = mx;
        }
        if (c == 0)
#pragma unroll
            for (int rr = 0; rr < 4; ++rr)
                pmaxs[(mtq * 16 + g * 4 + rr) * 2 + nq] = mloc[rr];
    }
    __syncthreads();   // B1 (all tb16/xb16 MFMA reads complete)

    // V epilogue: +bias, write v^T into tb16 region (T is dead)
    unsigned short* vt = tb16;
#pragma unroll
    for (int nt = 0; nt < 2; ++nt) {
        int dim = (w * 2 + nt) * 16 + c;
        float bias = sane(qkv_b[512 + dim]);
#pragma unroll
        for (int mt = 0; mt < 4; ++mt)
#pragma unroll
            for (int rr = 0; rr < 4; ++rr)
                vt[SWV(dim, mt * 16 + g * 4 + rr)] = f2bf(vacc[nt][mt][rr] + bias);
    }
    // softmax finish -> P
#pragma unroll
    for (int rr = 0; rr < 4; ++rr) {
        int row = mtq * 16 + g * 4 + rr;
        float m = fmaxf(pmaxs[row * 2], pmaxs[row * 2 + 1]);
        float p0 = __expf(sacc[0][rr] - m);
        float p1 = __expf(sacc[1][rr] - m);
        float s = p0 + p1;
        s += __shfl_xor(s, 1, 16);
        s += __shfl_xor(s, 2, 16);
        s += __shfl_xor(s, 4, 16);
        s += __shfl_xor(s, 8, 16);
        if (c == 0) psums[row * 2 + nq] = s;
        Pb[row * 72 + nq * 32 + c] = f2bf(p0);
        Pb[row * 72 + nq * 32 + 16 + c] = f2bf(p1);
    }
    __syncthreads();   // B2 (vt + P ready)

    // ======== P4: PV. wave w owns out dims 32w..32w+31. K = 64 tokens.
    f32x4 oacc[4][2];
#pragma unroll
    for (int mt = 0; mt < 4; ++mt)
#pragma unroll
        for (int n2 = 0; n2 < 2; ++n2) oacc[mt][n2] = f32x4{0.f, 0.f, 0.f, 0.f};
#pragma unroll
    for (int kt = 0; kt < 2; ++kt) {
        short8 bv[2];
#pragma unroll
        for (int n2 = 0; n2 < 2; ++n2)
            bv[n2] = *(const short8*)(vt + SWV(w * 32 + n2 * 16 + c, kt * 32 + g * 8));
#pragma unroll
        for (int mt = 0; mt < 4; ++mt) {
            short8 ap = *(const short8*)(Pb + (mt * 16 + c) * 72 + kt * 32 + g * 8);
#pragma unroll
            for (int n2 = 0; n2 < 2; ++n2)
                oacc[mt][n2] = __builtin_amdgcn_mfma_f32_16x16x32_bf16(ap, bv[n2], oacc[mt][n2], 0, 0, 0);
        }
    }
    // normalize, write ao into xb16 region (x is dead after B1/B2)
    unsigned short* ao = xb16;
#pragma unroll
    for (int mt = 0; mt < 4; ++mt)
#pragma unroll
        for (int rr = 0; rr < 4; ++rr) {
            int row = mt * 16 + g * 4 + rr;
            float inv = 1.0f / (psums[row * 2] + psums[row * 2 + 1]);
#pragma unroll
            for (int n2 = 0; n2 < 2; ++n2)
                ao[SWX(row, w * 32 + n2 * 16 + c)] = f2bf(oacc[mt][n2][rr] * inv);
        }
    __syncthreads();   // B3

    // ======== P5: proj = ao @ Wproj + b. wave w owns cols 32w..32w+31.
    f32x4 pacc[2][4];
#pragma unroll
    for (int n2 = 0; n2 < 2; ++n2)
#pragma unroll
        for (int mt = 0; mt < 4; ++mt) pacc[n2][mt] = f32x4{0.f, 0.f, 0.f, 0.f};
#pragma unroll
    for (int kt = 0; kt < 8; ++kt) {
        short8 aa[4];
#pragma unroll
        for (int mt = 0; mt < 4; ++mt)
            aa[mt] = *(const short8*)(ao + SWX(mt * 16 + c, kt * 32 + g * 8));
#pragma unroll
        for (int n2 = 0; n2 < 2; ++n2) {
            short8 bp = *(const short8*)(wp_pack + ((size_t)((w * 2 + n2) * 8 + kt) * 64 + lane) * 8);
#pragma unroll
            for (int mt = 0; mt < 4; ++mt)
                pacc[n2][mt] = __builtin_amdgcn_mfma_f32_16x16x32_bf16(aa[mt], bp, pacc[n2][mt], 0, 0, 0);
        }
    }
    __syncthreads();   // B4 (all ao/vt/Pb reads done before rbuf overlay)

    // bounce through rbuf (swizzled fp32) then contiguous float4 sweep out
    {
#pragma unroll
        for (int n2 = 0; n2 < 2; ++n2) {
            int col = (w * 2 + n2) * 16 + c;
            float pb = sane(proj_b[col]);
#pragma unroll
            for (int mt = 0; mt < 4; ++mt)
#pragma unroll
                for (int rr = 0; rr < 4; ++rr)
                    rbuf[SWR(mt * 16 + g * 4 + rr, col)] = pacc[n2][mt][rr] + pb;
        }
    }
    __syncthreads();   // B5

    float* ob = out + (size_t)b * 16384;
#pragma unroll
    for (int i = 0; i < 8; ++i) {
        int ch = tid + i * 512;
        float4 vv = *(const float4*)(rbuf + SWR(ch >> 6, (ch & 63) * 4));
        *(float4*)(ob + (ch >> 6) * 256 + (ch & 63) * 4) = vv;
    }
}

// -------------------------------------------------------------- launch ----
extern "C" void kernel_launch(void* const* d_in, const int* in_sizes, int n_in,
                              void* d_out, int out_size, void* d_ws, size_t ws_size,
                              hipStream_t stream) {
    const float* x      = (const float*)d_in[0];
    const float* theta  = (const float*)d_in[1];
    const float* qkv_w  = (const float*)d_in[2];
    const float* qkv_b  = (const float*)d_in[3];
    const float* proj_w = (const float*)d_in[4];
    const float* proj_b = (const float*)d_in[5];
    const float* a_p    = (const float*)d_in[6];
    const float* b_p    = (const float*)d_in[7];
    const float* a_r    = (const float*)d_in[8];
    const float* b_r    = (const float*)d_in[9];
    float* out = (float*)d_out;

    // workspace: m_pack 128K | wv_pack 128K | wp_pack 128K | qb2 2K | kb2 1K | btab 1M
    unsigned short* m_pack  = (unsigned short*)d_ws;
    unsigned short* wv_pack = m_pack + 65536;
    unsigned short* wp_pack = wv_pack + 65536;
    float* qb2  = (float*)((char*)d_ws + 393216);
    float* kb2  = (float*)((char*)d_ws + 395264);
    float* btab = (float*)((char*)d_ws + 396288);

    prep_all<<<1346, 256, 0, stream>>>(qkv_w, proj_w, qkv_b, theta,
                                       a_p, b_p, a_r, b_r,
                                       m_pack, wv_pack, wp_pack, qb2, kb2, btab);

    hipFuncSetAttribute(reinterpret_cast<const void*>(wattn_main),
                        hipFuncAttributeMaxDynamicSharedMemorySize, LDS_BYTES);
    wattn_main<<<4096, 512, LDS_BYTES, stream>>>(x, qkv_b, proj_b,
                                                 m_pack, wv_pack, wp_pack,
                                                 qb2, kb2, btab, out);
}